// Round 7
// baseline (186.978 us; speedup 1.0000x reference)
//
#include <hip/hip_runtime.h>

#define MA 64
#define F 128
#define NF 16
#define HID 512
#define LDU 136   // u / staged-h row stride (bf16 elems)
#define LDT 72    // w row stride
#define LDT1 520  // t1 half-buffer row stride

typedef float  float4v __attribute__((ext_vector_type(4)));
typedef short  short8  __attribute__((ext_vector_type(8)));

// pack two fp32 -> (bf16(y)<<16)|bf16(x), round-half-up via +0x8000 then v_perm
static __device__ __forceinline__ unsigned int pack2bf(float x, float y) {
    unsigned int a = __float_as_uint(x) + 0x8000u;
    unsigned int b = __float_as_uint(y) + 0x8000u;
    return __builtin_amdgcn_perm(b, a, 0x07060302u);
}
static __device__ __forceinline__ unsigned short f2bf1(float x) {
    return (unsigned short)((__float_as_uint(x) + 0x8000u) >> 16);
}

// ---- Pack W1 as A-frags of W1^T, W2 as A-frags of W2^T (direct global gather).
// A-frag (16x16x32): lane l holds A[m0+(l&15)][k0+(l>>4)*8+j], j=0..7.
__global__ void pack_frags(const float* __restrict__ W1, const float* __restrict__ W2,
                           unsigned short* __restrict__ w1p, unsigned short* __restrict__ w2p) {
    int gid  = blockIdx.x * 4 + (threadIdx.x >> 6);
    int lane = threadIdx.x & 63;
    int kq   = (lane >> 4) * 8;
    int arow = lane & 15;
    float v[8];
    if (gid < 68 * 32) {                       // W1: kt (68 over K=2176) x jt (32 over 512)
        int kt = gid >> 5, jt = gid & 31;
        const float* base = W1 + (size_t)(kt * 32 + kq) * HID + jt * 16 + arow;
        #pragma unroll
        for (int j = 0; j < 8; j++) v[j] = base[j * HID];
        uint4 o = { pack2bf(v[0], v[1]), pack2bf(v[2], v[3]),
                    pack2bf(v[4], v[5]), pack2bf(v[6], v[7]) };
        *(uint4*)(w1p + (size_t)gid * 512 + lane * 8) = o;
    } else {                                   // W2: kt (16 over J=512) x mt (8 over 128)
        int g2 = gid - 68 * 32;
        int kt = g2 >> 3, mt = g2 & 7;
        const float* base = W2 + (size_t)(kt * 32 + kq) * F + mt * 16 + arow;
        #pragma unroll
        for (int j = 0; j < 8; j++) v[j] = base[j * F];
        uint4 o = { pack2bf(v[0], v[1]), pack2bf(v[2], v[3]),
                    pack2bf(v[4], v[5]), pack2bf(v[6], v[7]) };
        *(uint4*)(w2p + (size_t)g2 * 512 + lane * 8) = o;
    }
}

// ---- Main fused kernel: TWO molecules per block, 512 threads = 8 waves ----
// LDS (bf16 elems): ub mol0 @0 (8704) | ub mol1 @8704 (8704) | wL mol0 @17408 (4608)
// | wL mol1 @22016 (4608). Single u buffer per molecule (u-store deferred past
// barrier 1). t1 (32x520=16640) overlays ub during GEMM2. Total 53248 B + r_lds 2 KB.
__launch_bounds__(512, 2)
__global__ void node_conv_mfma(const int* __restrict__ z, const float* __restrict__ rr,
        const float* __restrict__ h, const float* __restrict__ dist,
        const float* __restrict__ wid, const float* __restrict__ b1,
        const float* __restrict__ b2,
        const unsigned short* __restrict__ w1p, const unsigned short* __restrict__ w2p,
        float* __restrict__ out) {
    const int nb = blockIdx.x;                 // molecules 2nb, 2nb+1
    const int tid = threadIdx.x;
    const int lane = tid & 63;
    const int wave = tid >> 6;
    const int arow = lane & 15;
    const int quad = lane >> 4;
    const int kgrp = quad * 8;

    __shared__ __attribute__((aligned(16))) unsigned short lds[26624];
    __shared__ float r_lds[2][MA][4];          // xyz + mask per molecule

    const int N = gridDim.x * 2;
    const int n0 = nb * 2;
    const float* hg0 = h + (size_t)n0 * MA * F;

    // ---- z / r passthrough + r/mask staging (both molecules) ----
    if (tid < 2 * MA) {
        int zi = z[n0 * MA + tid];
        out[(size_t)n0 * MA + tid] = (float)zi;
        int mol = tid >> 6, a = tid & 63;
        r_lds[mol][a][0] = rr[(n0 * MA + tid) * 3 + 0];
        r_lds[mol][a][1] = rr[(n0 * MA + tid) * 3 + 1];
        r_lds[mol][a][2] = rr[(n0 * MA + tid) * 3 + 2];
        r_lds[mol][a][3] = (zi > -1) ? 1.0f : 0.0f;
    }
    if (tid < 2 * MA * 3)
        out[(size_t)N * MA + (size_t)n0 * MA * 3 + tid] = rr[(size_t)n0 * MA * 3 + tid];

    // ---- stage h -> ub (row-major bf16, both molecules) ----
    for (int i = tid; i < 2 * MA * F / 4; i += 512) {
        float4 v = ((const float4*)hg0)[i];
        int mol = i >> 11;                     // 2048 float4 per molecule
        int j = i & 2047;
        int a = j >> 5, c4 = (j & 31) * 4;
        uint2 pv = { pack2bf(v.x, v.y), pack2bf(v.z, v.w) };
        *(uint2*)&lds[mol * 8704 + a * LDU + c4] = pv;
    }
    // ---- hT A-fragments held in registers: lane holds h[b][c], c = wave*16+arow ----
    short8 ah[2][2];
    {
        int c = wave * 16 + arow;
        #pragma unroll
        for (int mol = 0; mol < 2; mol++) {
            const float* hm = hg0 + mol * MA * F;
            #pragma unroll
            for (int ks2 = 0; ks2 < 2; ks2++)
                #pragma unroll
                for (int j = 0; j < 8; j++)
                    ah[mol][ks2][j] = (short)f2bf1(hm[(size_t)(ks2 * 32 + kgrp + j) * F + c]);
        }
    }
    __syncthreads();                           // r_lds + staged h visible

    // ---- per-thread pairwise distances, mask folded in (d+1e4 -> exp underflows to 0) ----
    const int wa = tid >> 3;
    const int wb0 = (tid & 7) * 8;
    float dpre[2][8];
    #pragma unroll
    for (int mol = 0; mol < 2; mol++) {
        float ax = r_lds[mol][wa][0], ay = r_lds[mol][wa][1], az = r_lds[mol][wa][2];
        float am = r_lds[mol][wa][3];
        #pragma unroll
        for (int j = 0; j < 8; j++) {
            float dx = ax - r_lds[mol][wb0 + j][0];
            float dy = ay - r_lds[mol][wb0 + j][1];
            float dz = az - r_lds[mol][wb0 + j][2];
            float d = sqrtf(dx * dx + dy * dy + dz * dz + 1e-12f);
            float mm = am * r_lds[mol][wb0 + j][3];
            dpre[mol][j] = d + (1.0f - mm) * 1e4f;
        }
    }

    // ---- prime: w for filter 0 -> wL, and afr for seg 0 ----
    {
        float mu = dist[0];
        float isg = 1.0f / wid[0];
        #pragma unroll
        for (int mol = 0; mol < 2; mol++) {
            float e[8];
            #pragma unroll
            for (int j = 0; j < 8; j++) {
                float t = dpre[mol][j] - mu;
                e[j] = 5.0f * __expf(-t * t * isg);
            }
            uint4 wp = { pack2bf(e[0], e[1]), pack2bf(e[2], e[3]),
                         pack2bf(e[4], e[5]), pack2bf(e[6], e[7]) };
            *(uint4*)&lds[17408 + mol * 4608 + wa * LDT + wb0] = wp;
        }
    }
    short8 afr[2][4];
    {
        const unsigned short* p = w1p + ((size_t)(wave * 4) * 64 + lane) * 8;
        #pragma unroll
        for (int mt = 0; mt < 4; mt++) afr[0][mt] = *(const short8*)(p + mt * 512);
    }
    __syncthreads();                           // w filter 0 visible

    const float4v zf = {0.f, 0.f, 0.f, 0.f};
    float4v acc[2][4][4];                      // [mol][j-tile in wave's 64-slab][a-tile]
    #pragma unroll
    for (int m = 0; m < 2; m++)
        #pragma unroll
        for (int i = 0; i < 4; i++)
            #pragma unroll
            for (int jv = 0; jv < 4; jv++) acc[m][i][jv] = zf;

    // ---- main loop: 17 K-segments of 128.  Schedule (0-based filters):
    //  iter f A: [GEMM1 seg f (reads ub = u_{f-1} or h)  +  u-GEMM: u_f = hT @ w_f
    //             (reads wL + ah regs; result packed into udp REGS, no LDS write)]
    //          -> barrier 1 (all ub + wL reads drained)
    //  iter f B: [udp -> ub (overwrite);  exp w_{f+1} -> wL (f <= NF-2)]
    //          -> barrier 2 (skipped at f = NF)
    for (int f = 0; f <= NF; f++) {
        const unsigned short* pA = w1p + (((size_t)(f * 128) + wave * 4) * 64 + lane) * 8;

        // GEMM1 seg f: A = w1p frags (reg-pipelined, wraps to seg f+1), B = ub frags
        #pragma unroll
        for (int ks = 0; ks < 4; ks++) {
            short8* acur = afr[ks & 1];
            short8* anxt = afr[(ks + 1) & 1];
            {   // prefetch: ks<3 -> seg f ks+1; ks==3 -> seg f+1 ks0 (clamped at f=16)
                const unsigned short* pN = (ks < 3) ? (pA + (ks + 1) * 16384)
                                                    : (pA + ((f < NF) ? 65536 : 0));
                #pragma unroll
                for (int mt = 0; mt < 4; mt++) anxt[mt] = *(const short8*)(pN + mt * 512);
            }
            short8 bfr[2][4];
            #pragma unroll
            for (int mol = 0; mol < 2; mol++)
                #pragma unroll
                for (int at = 0; at < 4; at++)
                    bfr[mol][at] = *(const short8*)&lds[mol * 8704 + (at * 16 + arow) * LDU + ks * 32 + kgrp];
            #pragma unroll
            for (int mt = 0; mt < 4; mt++)
                #pragma unroll
                for (int mol = 0; mol < 2; mol++)
                    #pragma unroll
                    for (int at = 0; at < 4; at++)
                        acc[mol][mt][at] = __builtin_amdgcn_mfma_f32_16x16x32_bf16(
                            acur[mt], bfr[mol][at], acc[mol][mt][at], 0, 0, 0);
        }

        uint2 udp[2][4];                       // packed u_f fragments (held across barrier 1)
        if (f < NF) {
            // u-GEMM (same interval): u_f^T = hT @ w_f (w symmetric); NO LDS write here
            #pragma unroll
            for (int mol = 0; mol < 2; mol++) {
                float4v ud[4];
                #pragma unroll
                for (int at = 0; at < 4; at++) ud[at] = zf;
                #pragma unroll
                for (int ks2 = 0; ks2 < 2; ks2++)
                    #pragma unroll
                    for (int at = 0; at < 4; at++) {
                        short8 bw = *(const short8*)&lds[17408 + mol * 4608 + (at * 16 + arow) * LDT + ks2 * 32 + kgrp];
                        ud[at] = __builtin_amdgcn_mfma_f32_16x16x32_bf16(ah[mol][ks2], bw, ud[at], 0, 0, 0);
                    }
                #pragma unroll
                for (int at = 0; at < 4; at++)
                    udp[mol][at] = (uint2){ pack2bf(ud[at][0], ud[at][1]),
                                            pack2bf(ud[at][2], ud[at][3]) };
            }
        }
        __syncthreads();                       // barrier 1: ub + wL reads done

        if (f < NF) {
            // B: store u_f over ub (readers drained); exp w_{f+1} -> wL
            #pragma unroll
            for (int mol = 0; mol < 2; mol++)
                #pragma unroll
                for (int at = 0; at < 4; at++)
                    *(uint2*)&lds[mol * 8704 + (at * 16 + arow) * LDU + wave * 16 + quad * 4] = udp[mol][at];

            if (f <= NF - 2) {
                float mu = dist[f + 1];
                float isg = 1.0f / wid[f + 1];
                #pragma unroll
                for (int mol = 0; mol < 2; mol++) {
                    float e[8];
                    #pragma unroll
                    for (int j = 0; j < 8; j++) {
                        float t = dpre[mol][j] - mu;
                        e[j] = 5.0f * __expf(-t * t * isg);
                    }
                    uint4 wp = { pack2bf(e[0], e[1]), pack2bf(e[2], e[3]),
                                 pack2bf(e[4], e[5]), pack2bf(e[6], e[7]) };
                    *(uint4*)&lds[17408 + mol * 4608 + wa * LDT + wb0] = wp;
                }
            }
            __syncthreads();                   // barrier 2: u_f + w_{f+1} visible
        }
    }

    // ---- GEMM2: out = h + 0.1*mask*(silu(t1) @ W2 + b2); 4 half-tiles (2 mol x 2) ----
    float4 b1v[4];
    #pragma unroll
    for (int mt = 0; mt < 4; mt++)
        b1v[mt] = *(const float4*)&b1[wave * 64 + mt * 16 + quad * 4];
    float* outh0 = out + (size_t)N * MA * 4 + (size_t)n0 * MA * F;

    #pragma unroll
    for (int half = 0; half < 4; half++) {
        const int mol = half >> 1, hh = half & 1;
        if (half) __syncthreads();             // prior GEMM2 reads of t1 done
        #pragma unroll
        for (int mt = 0; mt < 4; mt++) {
            #pragma unroll
            for (int ai = 0; ai < 2; ai++) {
                const int at = hh * 2 + ai;
                float xs[4];
                #pragma unroll
                for (int r = 0; r < 4; r++) {
                    float x = acc[mol][mt][at][r] + ((const float*)&b1v[mt])[r];
                    xs[r] = x / (1.0f + __expf(-x));
                }
                uint2 pv = { pack2bf(xs[0], xs[1]), pack2bf(xs[2], xs[3]) };
                *(uint2*)&lds[(ai * 16 + arow) * LDT1 + wave * 64 + mt * 16 + quad * 4] = pv;
            }
        }
        __syncthreads();                       // t1 half visible

        float4v g2[2] = {zf, zf};
        for (int ks = 0; ks < 16; ks++) {
            short8 aw2 = *(const short8*)(w2p + ((size_t)(ks * 8 + wave) * 64 + lane) * 8);
            #pragma unroll
            for (int n2 = 0; n2 < 2; n2++) {
                short8 bt = *(const short8*)&lds[(n2 * 16 + arow) * LDT1 + ks * 32 + kgrp];
                g2[n2] = __builtin_amdgcn_mfma_f32_16x16x32_bf16(aw2, bt, g2[n2], 0, 0, 0);
            }
        }
        // D[m=c][n=a]: a = hh*32+n2*16+arow, c = wave*16+quad*4 + r
        const float* hgm = hg0 + mol * MA * F;
        float* outh = outh0 + mol * MA * F;
        #pragma unroll
        for (int n2 = 0; n2 < 2; n2++) {
            int a = hh * 32 + n2 * 16 + arow;
            int c0 = wave * 16 + quad * 4;
            float m = r_lds[mol][a][3] * 0.1f;
            float4 hv = *(const float4*)&hgm[a * F + c0];
            float4 b2v = *(const float4*)&b2[c0];
            float4 res;
            res.x = hv.x + (g2[n2][0] + b2v.x) * m;
            res.y = hv.y + (g2[n2][1] + b2v.y) * m;
            res.z = hv.z + (g2[n2][2] + b2v.z) * m;
            res.w = hv.w + (g2[n2][3] + b2v.w) * m;
            *(float4*)&outh[(size_t)a * F + c0] = res;
        }
    }
}

extern "C" void kernel_launch(void* const* d_in, const int* in_sizes, int n_in,
                              void* d_out, int out_size, void* d_ws, size_t ws_size,
                              hipStream_t stream) {
    const int*   z    = (const int*)d_in[0];
    const float* rr   = (const float*)d_in[1];
    const float* h    = (const float*)d_in[2];
    const float* dist = (const float*)d_in[3];
    const float* wid  = (const float*)d_in[4];
    const float* W1   = (const float*)d_in[5];
    const float* b1   = (const float*)d_in[6];
    const float* W2   = (const float*)d_in[7];
    const float* b2   = (const float*)d_in[8];
    float* out = (float*)d_out;

    int Nmol = in_sizes[0] / MA;                           // 512 molecules

    unsigned short* w1p = (unsigned short*)d_ws;           // 68*32*512 = 1,114,112 bf16
    unsigned short* w2p = w1p + (size_t)68 * 32 * 512;     // 128*512   = 65,536 bf16

    pack_frags<<<576, 256, 0, stream>>>(W1, W2, w1p, w2p);
    node_conv_mfma<<<Nmol / 2, 512, 0, stream>>>(z, rr, h, dist, wid, b1, b2, w1p, w2p, out);
}

// Round 8
// 159.455 us; speedup vs baseline: 1.1726x; 1.1726x over previous
//
#include <hip/hip_runtime.h>

#define MA 64
#define F 128
#define NF 16
#define HID 512
#define LDUB 136   // ub row stride BYTES (128 fp8 + 8 pad)
#define UBSZ 8704  // per-mol ub bytes
#define WLB  17408 // wL base byte offset
#define WLSZ 9216  // per-mol wL bytes (64 rows x 144 B)
#define LDWB 144   // wL row stride bytes (72 bf16 elems)
#define LDT1B 528  // t1 row stride bytes (512 fp8 + 16 pad)

typedef float  float4v __attribute__((ext_vector_type(4)));
typedef short  short8  __attribute__((ext_vector_type(8)));

// pack two fp32 -> (bf16(y)<<16)|bf16(x), round-half-up via +0x8000 then v_perm
static __device__ __forceinline__ unsigned int pack2bf(float x, float y) {
    unsigned int a = __float_as_uint(x) + 0x8000u;
    unsigned int b = __float_as_uint(y) + 0x8000u;
    return __builtin_amdgcn_perm(b, a, 0x07060302u);
}
static __device__ __forceinline__ unsigned short f2bf1(float x) {
    return (unsigned short)((__float_as_uint(x) + 0x8000u) >> 16);
}
// pack 4 fp32 -> 4 fp8 e4m3 (RNE, saturating) in one dword
static __device__ __forceinline__ unsigned int pk4fp8(float a, float b, float c, float d) {
    int p = __builtin_amdgcn_cvt_pk_fp8_f32(a, b, 0, false);
    p = __builtin_amdgcn_cvt_pk_fp8_f32(c, d, p, true);
    return (unsigned int)p;
}

// ---- Pack W1 as fp8 A-frags of W1^T, W2 as fp8 A-frags of W2^T (direct gather).
// A-frag (16x16x32 fp8): lane l holds A[m0+(l&15)][k0+(l>>4)*8+j], j=0..7 (8 bytes).
__global__ void pack_frags(const float* __restrict__ W1, const float* __restrict__ W2,
                           unsigned char* __restrict__ w1p, unsigned char* __restrict__ w2p) {
    int gid  = blockIdx.x * 4 + (threadIdx.x >> 6);
    int lane = threadIdx.x & 63;
    int kq   = (lane >> 4) * 8;
    int arow = lane & 15;
    float v[8];
    if (gid < 68 * 32) {                       // W1: kt (68 over K=2176) x jt (32 over 512)
        int kt = gid >> 5, jt = gid & 31;
        const float* base = W1 + (size_t)(kt * 32 + kq) * HID + jt * 16 + arow;
        #pragma unroll
        for (int j = 0; j < 8; j++) v[j] = base[j * HID];
        uint2 o = { pk4fp8(v[0], v[1], v[2], v[3]), pk4fp8(v[4], v[5], v[6], v[7]) };
        *(uint2*)(w1p + ((size_t)gid * 64 + lane) * 8) = o;
    } else {                                   // W2: kt (16 over J=512) x mt (8 over 128)
        int g2 = gid - 68 * 32;
        int kt = g2 >> 3, mt = g2 & 7;
        const float* base = W2 + (size_t)(kt * 32 + kq) * F + mt * 16 + arow;
        #pragma unroll
        for (int j = 0; j < 8; j++) v[j] = base[j * F];
        uint2 o = { pk4fp8(v[0], v[1], v[2], v[3]), pk4fp8(v[4], v[5], v[6], v[7]) };
        *(uint2*)(w2p + ((size_t)g2 * 64 + lane) * 8) = o;
    }
}

// ---- Main fused kernel: TWO molecules per block, 512 threads = 8 waves ----
// LDS bytes: ub mol0 @0 (8704) | ub mol1 @8704 (8704) | wL mol0 @17408 (9216)
// | wL mol1 @26624 (9216) = 35840 B. t1 (32 x 528 = 16896 B) overlays ub in GEMM2.
__launch_bounds__(512, 2)
__global__ void node_conv_mfma(const int* __restrict__ z, const float* __restrict__ rr,
        const float* __restrict__ h, const float* __restrict__ dist,
        const float* __restrict__ wid, const float* __restrict__ b1,
        const float* __restrict__ b2,
        const unsigned char* __restrict__ w1p, const unsigned char* __restrict__ w2p,
        float* __restrict__ out) {
    const int nb = blockIdx.x;                 // molecules 2nb, 2nb+1
    const int tid = threadIdx.x;
    const int lane = tid & 63;
    const int wave = tid >> 6;
    const int arow = lane & 15;
    const int quad = lane >> 4;
    const int kgrp = quad * 8;

    __shared__ __attribute__((aligned(16))) unsigned char lds[35840];
    __shared__ float r_lds[2][MA][4];          // xyz + mask per molecule

    const int N = gridDim.x * 2;
    const int n0 = nb * 2;
    const float* hg0 = h + (size_t)n0 * MA * F;

    // ---- z / r passthrough + r/mask staging (both molecules) ----
    if (tid < 2 * MA) {
        int zi = z[n0 * MA + tid];
        out[(size_t)n0 * MA + tid] = (float)zi;
        int mol = tid >> 6, a = tid & 63;
        r_lds[mol][a][0] = rr[(n0 * MA + tid) * 3 + 0];
        r_lds[mol][a][1] = rr[(n0 * MA + tid) * 3 + 1];
        r_lds[mol][a][2] = rr[(n0 * MA + tid) * 3 + 2];
        r_lds[mol][a][3] = (zi > -1) ? 1.0f : 0.0f;
    }
    if (tid < 2 * MA * 3)
        out[(size_t)N * MA + (size_t)n0 * MA * 3 + tid] = rr[(size_t)n0 * MA * 3 + tid];

    // ---- stage h -> ub (row-major fp8, both molecules) ----
    for (int i = tid; i < 2 * MA * F / 4; i += 512) {
        float4 v = ((const float4*)hg0)[i];
        int mol = i >> 11;                     // 2048 float4 per molecule
        int j = i & 2047;
        int a = j >> 5, c4 = (j & 31) * 4;
        *(unsigned int*)&lds[mol * UBSZ + a * LDUB + c4] = pk4fp8(v.x, v.y, v.z, v.w);
    }
    // ---- hT A-fragments held in registers (bf16): lane holds h[b][c], c = wave*16+arow ----
    short8 ah[2][2];
    {
        int c = wave * 16 + arow;
        #pragma unroll
        for (int mol = 0; mol < 2; mol++) {
            const float* hm = hg0 + mol * MA * F;
            #pragma unroll
            for (int ks2 = 0; ks2 < 2; ks2++)
                #pragma unroll
                for (int j = 0; j < 8; j++)
                    ah[mol][ks2][j] = (short)f2bf1(hm[(size_t)(ks2 * 32 + kgrp + j) * F + c]);
        }
    }
    __syncthreads();                           // r_lds + staged h visible

    // ---- per-thread pairwise distances, mask folded in (d+1e4 -> exp underflows to 0) ----
    const int wa = tid >> 3;
    const int wb0 = (tid & 7) * 8;
    float dpre[2][8];
    #pragma unroll
    for (int mol = 0; mol < 2; mol++) {
        float ax = r_lds[mol][wa][0], ay = r_lds[mol][wa][1], az = r_lds[mol][wa][2];
        float am = r_lds[mol][wa][3];
        #pragma unroll
        for (int j = 0; j < 8; j++) {
            float dx = ax - r_lds[mol][wb0 + j][0];
            float dy = ay - r_lds[mol][wb0 + j][1];
            float dz = az - r_lds[mol][wb0 + j][2];
            float d = sqrtf(dx * dx + dy * dy + dz * dz + 1e-12f);
            float mm = am * r_lds[mol][wb0 + j][3];
            dpre[mol][j] = d + (1.0f - mm) * 1e4f;
        }
    }

    // ---- prime: w filter 0 -> wL (bf16), afr for seg 0 ----
    {
        float mu = dist[0];
        float isg = 1.0f / wid[0];
        #pragma unroll
        for (int mol = 0; mol < 2; mol++) {
            float e[8];
            #pragma unroll
            for (int j = 0; j < 8; j++) {
                float t = dpre[mol][j] - mu;
                e[j] = 5.0f * __expf(-t * t * isg);
            }
            uint4 wp = { pack2bf(e[0], e[1]), pack2bf(e[2], e[3]),
                         pack2bf(e[4], e[5]), pack2bf(e[6], e[7]) };
            *(uint4*)&lds[WLB + mol * WLSZ + wa * LDWB + wb0 * 2] = wp;
        }
    }
    long afr[2][4];
    {
        const unsigned char* p = w1p + ((size_t)(wave * 4) * 64 + lane) * 8;
        #pragma unroll
        for (int mt = 0; mt < 4; mt++) afr[0][mt] = *(const long*)(p + mt * 512);
    }
    __syncthreads();                           // w filter 0 visible

    const float4v zf = {0.f, 0.f, 0.f, 0.f};
    float4v acc[2][4][4];                      // [mol][j-tile in wave's 64-slab][a-tile]
    #pragma unroll
    for (int m = 0; m < 2; m++)
        #pragma unroll
        for (int i = 0; i < 4; i++)
            #pragma unroll
            for (int jv = 0; jv < 4; jv++) acc[m][i][jv] = zf;

    // ---- main loop: 17 K-segments of 128.  Schedule (0-based filters):
    //  iter f A: [GEMM1 seg f (fp8, reads ub)  +  u-GEMM u_f = hT @ w_f (bf16, reads wL;
    //             result -> udp regs)]                         -> barrier 1
    //  iter f B: [udp -> ub (fp8);  exp w_{f+1} -> wL]         -> barrier 2
    for (int f = 0; f <= NF; f++) {
        const unsigned char* pA = w1p + (((size_t)(f * 128) + wave * 4) * 64 + lane) * 8;

        // GEMM1 seg f: A = w1p fp8 frags (global, pipelined), B = ub fp8 frags (LDS, dbuf)
        long bfr[2][2][4];
        #pragma unroll
        for (int mol = 0; mol < 2; mol++)
            #pragma unroll
            for (int at = 0; at < 4; at++)
                bfr[0][mol][at] = *(const long*)&lds[mol * UBSZ + (at * 16 + arow) * LDUB + kgrp];
        #pragma unroll
        for (int ks = 0; ks < 4; ks++) {
            long* acur = afr[ks & 1];
            long* anxt = afr[(ks + 1) & 1];
            {   // A prefetch: ks<3 -> seg f ks+1; ks==3 -> seg f+1 ks0 (clamped at f=16)
                const unsigned char* pN = (ks < 3) ? (pA + (ks + 1) * 16384)
                                                   : (pA + ((f < NF) ? 65536 : 0));
                #pragma unroll
                for (int mt = 0; mt < 4; mt++) anxt[mt] = *(const long*)(pN + mt * 512);
            }
            long (*bcur)[4] = bfr[ks & 1];
            long (*bnxt)[4] = bfr[(ks + 1) & 1];
            if (ks < 3) {                      // B prefetch within segment
                #pragma unroll
                for (int mol = 0; mol < 2; mol++)
                    #pragma unroll
                    for (int at = 0; at < 4; at++)
                        bnxt[mol][at] = *(const long*)&lds[mol * UBSZ + (at * 16 + arow) * LDUB + (ks + 1) * 32 + kgrp];
            }
            #pragma unroll
            for (int mt = 0; mt < 4; mt++)
                #pragma unroll
                for (int mol = 0; mol < 2; mol++)
                    #pragma unroll
                    for (int at = 0; at < 4; at++)
                        acc[mol][mt][at] = __builtin_amdgcn_mfma_f32_16x16x32_fp8_fp8(
                            acur[mt], bcur[mol][at], acc[mol][mt][at], 0, 0, 0);
        }

        unsigned int udp[2][4];                // packed fp8 u_f fragments (held over barrier 1)
        if (f < NF) {
            // u-GEMM: u_f^T = hT @ w_f (bf16, w symmetric); no LDS write here
            #pragma unroll
            for (int mol = 0; mol < 2; mol++) {
                float4v ud[4];
                #pragma unroll
                for (int at = 0; at < 4; at++) ud[at] = zf;
                #pragma unroll
                for (int ks2 = 0; ks2 < 2; ks2++)
                    #pragma unroll
                    for (int at = 0; at < 4; at++) {
                        short8 bw = *(const short8*)&lds[WLB + mol * WLSZ + (at * 16 + arow) * LDWB + (ks2 * 32 + kgrp) * 2];
                        ud[at] = __builtin_amdgcn_mfma_f32_16x16x32_bf16(ah[mol][ks2], bw, ud[at], 0, 0, 0);
                    }
                #pragma unroll
                for (int at = 0; at < 4; at++)
                    udp[mol][at] = pk4fp8(ud[at][0], ud[at][1], ud[at][2], ud[at][3]);
            }
        }
        __syncthreads();                       // barrier 1: ub + wL reads done

        if (f < NF) {
            // B: store u_f over ub (readers drained); exp w_{f+1} -> wL
            #pragma unroll
            for (int mol = 0; mol < 2; mol++)
                #pragma unroll
                for (int at = 0; at < 4; at++)
                    *(unsigned int*)&lds[mol * UBSZ + (at * 16 + arow) * LDUB + wave * 16 + quad * 4] = udp[mol][at];

            if (f <= NF - 2) {
                float mu = dist[f + 1];
                float isg = 1.0f / wid[f + 1];
                #pragma unroll
                for (int mol = 0; mol < 2; mol++) {
                    float e[8];
                    #pragma unroll
                    for (int j = 0; j < 8; j++) {
                        float t = dpre[mol][j] - mu;
                        e[j] = 5.0f * __expf(-t * t * isg);
                    }
                    uint4 wp = { pack2bf(e[0], e[1]), pack2bf(e[2], e[3]),
                                 pack2bf(e[4], e[5]), pack2bf(e[6], e[7]) };
                    *(uint4*)&lds[WLB + mol * WLSZ + wa * LDWB + wb0 * 2] = wp;
                }
            }
            __syncthreads();                   // barrier 2: u_f + w_{f+1} visible
        }
    }

    // ---- GEMM2 (fp8): out = h + 0.1*mask*(silu(t1) @ W2 + b2); 4 half-tiles ----
    float4 b1v[4];
    #pragma unroll
    for (int mt = 0; mt < 4; mt++)
        b1v[mt] = *(const float4*)&b1[wave * 64 + mt * 16 + quad * 4];
    float* outh0 = out + (size_t)N * MA * 4 + (size_t)n0 * MA * F;

    #pragma unroll
    for (int half = 0; half < 4; half++) {
        const int mol = half >> 1, hh = half & 1;
        if (half) __syncthreads();             // prior GEMM2 reads of t1 done
        #pragma unroll
        for (int mt = 0; mt < 4; mt++) {
            #pragma unroll
            for (int ai = 0; ai < 2; ai++) {
                const int at = hh * 2 + ai;
                float xs[4];
                #pragma unroll
                for (int r = 0; r < 4; r++) {
                    float x = acc[mol][mt][at][r] + ((const float*)&b1v[mt])[r];
                    xs[r] = x / (1.0f + __expf(-x));
                }
                *(unsigned int*)&lds[(ai * 16 + arow) * LDT1B + wave * 64 + mt * 16 + quad * 4] =
                    pk4fp8(xs[0], xs[1], xs[2], xs[3]);
            }
        }
        __syncthreads();                       // t1 half visible

        float4v g2[2] = {zf, zf};
        for (int ks = 0; ks < 16; ks++) {
            long aw2 = *(const long*)(w2p + ((size_t)(ks * 8 + wave) * 64 + lane) * 8);
            #pragma unroll
            for (int n2 = 0; n2 < 2; n2++) {
                long bt = *(const long*)&lds[(n2 * 16 + arow) * LDT1B + ks * 32 + kgrp];
                g2[n2] = __builtin_amdgcn_mfma_f32_16x16x32_fp8_fp8(aw2, bt, g2[n2], 0, 0, 0);
            }
        }
        // D[m=c][n=a]: a = hh*32+n2*16+arow, c = wave*16+quad*4 + r
        const float* hgm = hg0 + mol * MA * F;
        float* outh = outh0 + mol * MA * F;
        #pragma unroll
        for (int n2 = 0; n2 < 2; n2++) {
            int a = hh * 32 + n2 * 16 + arow;
            int c0 = wave * 16 + quad * 4;
            float m = r_lds[mol][a][3] * 0.1f;
            float4 hv = *(const float4*)&hgm[a * F + c0];
            float4 b2v = *(const float4*)&b2[c0];
            float4 res;
            res.x = hv.x + (g2[n2][0] + b2v.x) * m;
            res.y = hv.y + (g2[n2][1] + b2v.y) * m;
            res.z = hv.z + (g2[n2][2] + b2v.z) * m;
            res.w = hv.w + (g2[n2][3] + b2v.w) * m;
            *(float4*)&outh[(size_t)a * F + c0] = res;
        }
    }
}

extern "C" void kernel_launch(void* const* d_in, const int* in_sizes, int n_in,
                              void* d_out, int out_size, void* d_ws, size_t ws_size,
                              hipStream_t stream) {
    const int*   z    = (const int*)d_in[0];
    const float* rr   = (const float*)d_in[1];
    const float* h    = (const float*)d_in[2];
    const float* dist = (const float*)d_in[3];
    const float* wid  = (const float*)d_in[4];
    const float* W1   = (const float*)d_in[5];
    const float* b1   = (const float*)d_in[6];
    const float* W2   = (const float*)d_in[7];
    const float* b2   = (const float*)d_in[8];
    float* out = (float*)d_out;

    int Nmol = in_sizes[0] / MA;                           // 512 molecules

    unsigned char* w1p = (unsigned char*)d_ws;             // 68*32*64*8 = 1,114,112 B
    unsigned char* w2p = w1p + (size_t)68 * 32 * 64 * 8;   // 16*8*64*8  = 65,536 B

    pack_frags<<<576, 256, 0, stream>>>(W1, W2, w1p, w2p);
    node_conv_mfma<<<Nmol / 2, 512, 0, stream>>>(z, rr, h, dist, wid, b1, b2, w1p, w2p, out);
}